// Round 6
// baseline (376.090 us; speedup 1.0000x reference)
//
#include <hip/hip_runtime.h>

constexpr int NS = 64;          // samples
constexpr int NA = 64;          // agents per sample
constexpr int NN = NS * NA;     // 4096 nodes
constexpr int FD = 128;         // feature dim
constexpr int ZD = 2 * FD + 2;  // 258
constexpr int FS = 16;          // feature-slice width per block
constexpr int NB = NS * (FD / FS); // 512 blocks = (sample, f-slice) == NT (1:1 barrier watch)
constexpr int NT = 512;         // threads per block
constexpr int XPAD = 132;       // xs row stride: 528B = 33*16 (float4-aligned), +4 bank skew
constexpr float BN_EPS = 1e-5f;
constexpr float L2E = 1.44269504088896f;
constexpr float LN2 = 0.69314718055995f;
constexpr unsigned MAGIC1 = 0x51C6A3B7u;   // non-repeating-byte magics: poison-collision
constexpr unsigned MAGIC2 = 0x9D24E58Fu;   // risk ~2^-32 per slot

// Manual grid barrier (regular launch; co-residency by construction:
// 512 blocks x 74.5KB LDS = exactly 2 blocks/CU x 256 CU, launch_bounds(512,4)).
// Block bid release-stores slots[bid]=magic; thread t acquire-spins on slots[t]
// (NB==NT, 1:1). Equality-vs-magic needs no counter init (ws is poisoned).
__device__ __forceinline__ void grid_barrier(unsigned* slots, unsigned magic,
                                             int tid, int bid)
{
    __threadfence();            // my stores visible device-wide
    __syncthreads();            // whole block done + fenced
    if (tid == 0)
        __hip_atomic_store(&slots[bid], magic, __ATOMIC_RELEASE,
                           __HIP_MEMORY_SCOPE_AGENT);
    while (__hip_atomic_load(&slots[tid], __ATOMIC_ACQUIRE,
                             __HIP_MEMORY_SCOPE_AGENT) != magic)
        __builtin_amdgcn_s_sleep(8);
    __syncthreads();            // all threads saw all blocks (L1 inv'd by acquires)
}

// Stage this block's 16-feature weight slice into LDS (R3-proven path):
// wlds[k][fr] = {Wf[f][k], Wf[f][k+128], Ws[f][k], Ws[f][k+128]}.
// Reads: 16-row gather, L1/L2-hot (132KB slab shared by 64 blocks).
// Writes: contiguous ds_write_b128, 2-way bank alias (free).
__device__ __forceinline__ void stage_w(
    float4 (*wlds)[FS], const float* __restrict__ Wf, const float* __restrict__ Ws,
    int fq, int tid)
{
    for (int i = tid; i < FD * FS; i += NT) {
        int k = i >> 4, fr = i & (FS - 1);
        int row = (fq * FS + fr) * ZD;
        wlds[k][fr] = make_float4(Wf[row + k], Wf[row + FD + k],
                                  Ws[row + k], Ws[row + FD + k]);
    }
}

// Fused CGConv layer for block (s, fq): GEMM (P exp-domain -> VGPRs, Q -> 8KB
// LDS tile; x float4 from LDS, W b128 from LDS wlds = 6 ds_read_b128 per
// 4k-chunk), then in-block edge aggregation + BN partial stores (no atomics).
// agg store optional (layer 2 keeps its output in registers via aOut0/aOut1).
__device__ __forceinline__ void layer_body(
    const float (*xs)[XPAD], const float2* cs, float2 (*q)[FS],
    const float4 (*wlds)[FS],
    const float* __restrict__ Wf, const float* __restrict__ Ws,
    const float* __restrict__ bf, const float* __restrict__ bs,
    int tid, int s, int fq,
    float* __restrict__ agg, float* __restrict__ pS, float* __restrict__ pSS,
    float& aOut0, float& aOut1)
{
    const int fl = tid & (FS - 1);
    const int ig = tid >> 4;            // 0..31 -> nodes {ig, ig+32}
    const int f  = fq * FS + fl;
    const int base = s * NA;

    float aPf0=0.f,aQf0=0.f,aPs0=0.f,aQs0=0.f;
    float aPf1=0.f,aQf1=0.f,aPs1=0.f,aQs1=0.f;
    #pragma unroll 2
    for (int k = 0; k < FD; k += 4) {
        float4 x0 = *(const float4*)&xs[ig][k];       // bcast across 16 fl: free
        float4 x1 = *(const float4*)&xs[ig + 32][k];
        float4 w0 = wlds[k + 0][fl];                  // 256B/wave, 2-way alias
        float4 w1 = wlds[k + 1][fl];
        float4 w2 = wlds[k + 2][fl];
        float4 w3 = wlds[k + 3][fl];
        aPf0 = fmaf(x0.x, w0.x, aPf0); aQf0 = fmaf(x0.x, w0.y, aQf0);
        aPs0 = fmaf(x0.x, w0.z, aPs0); aQs0 = fmaf(x0.x, w0.w, aQs0);
        aPf1 = fmaf(x1.x, w0.x, aPf1); aQf1 = fmaf(x1.x, w0.y, aQf1);
        aPs1 = fmaf(x1.x, w0.z, aPs1); aQs1 = fmaf(x1.x, w0.w, aQs1);

        aPf0 = fmaf(x0.y, w1.x, aPf0); aQf0 = fmaf(x0.y, w1.y, aQf0);
        aPs0 = fmaf(x0.y, w1.z, aPs0); aQs0 = fmaf(x0.y, w1.w, aQs0);
        aPf1 = fmaf(x1.y, w1.x, aPf1); aQf1 = fmaf(x1.y, w1.y, aQf1);
        aPs1 = fmaf(x1.y, w1.z, aPs1); aQs1 = fmaf(x1.y, w1.w, aQs1);

        aPf0 = fmaf(x0.z, w2.x, aPf0); aQf0 = fmaf(x0.z, w2.y, aQf0);
        aPs0 = fmaf(x0.z, w2.z, aPs0); aQs0 = fmaf(x0.z, w2.w, aQs0);
        aPf1 = fmaf(x1.z, w2.x, aPf1); aQf1 = fmaf(x1.z, w2.y, aQf1);
        aPs1 = fmaf(x1.z, w2.z, aPs1); aQs1 = fmaf(x1.z, w2.w, aQs1);

        aPf0 = fmaf(x0.w, w3.x, aPf0); aQf0 = fmaf(x0.w, w3.y, aQf0);
        aPs0 = fmaf(x0.w, w3.z, aPs0); aQs0 = fmaf(x0.w, w3.w, aQs0);
        aPf1 = fmaf(x1.w, w3.x, aPf1); aQf1 = fmaf(x1.w, w3.y, aQf1);
        aPs1 = fmaf(x1.w, w3.z, aPs1); aQs1 = fmaf(x1.w, w3.w, aQs1);
    }
    float we0 = Wf[f*ZD + 2*FD], we1 = Wf[f*ZD + 2*FD + 1];
    float ws0 = Ws[f*ZD + 2*FD], ws1 = Ws[f*ZD + 2*FD + 1];
    float bfv = bf[f], bsv = bs[f];
    float2 c0 = cs[ig], c1 = cs[ig + 32];
    float cf0 = c0.x*we0 + c0.y*we1, cg0 = c0.x*ws0 + c0.y*ws1;
    float cf1 = c1.x*we0 + c1.y*we1, cg1 = c1.x*ws0 + c1.y*ws1;
    float Pf0 = aPf0 + cf0 + bfv, Ps0 = aPs0 + cg0 + bsv;
    float Pf1 = aPf1 + cf1 + bfv, Ps1 = aPs1 + cg1 + bsv;
    float Qf0 = aQf0 - cf0,       Qs0 = aQs0 - cg0;
    float Qf1 = aQf1 - cf1,       Qs1 = aQs1 - cg1;
    // exp-domain: sigma = rcp(1 + e^{-P}e^{-Q}), softplus*log2e = log2(1 + e^{Ps}e^{Qs})
    float2 p0 = make_float2(__builtin_amdgcn_exp2f(-Pf0*L2E), __builtin_amdgcn_exp2f(Ps0*L2E));
    float2 p1 = make_float2(__builtin_amdgcn_exp2f(-Pf1*L2E), __builtin_amdgcn_exp2f(Ps1*L2E));
    q[ig][fl]    = make_float2(__builtin_amdgcn_exp2f(-Qf0*L2E), __builtin_amdgcn_exp2f(Qs0*L2E));
    q[ig+32][fl] = make_float2(__builtin_amdgcn_exp2f(-Qf1*L2E), __builtin_amdgcn_exp2f(Qs1*L2E));
    __syncthreads();

    // ---- edge aggregation: i in {ig, ig+32}, all 64 j, dual chains ----
    float a0=0.f, a1=0.f, b0=0.f, b1=0.f;
    #pragma unroll 4
    for (int j = 0; j < NA; j += 2) {
        float2 qa = q[j][fl];            // same-address bcast per lane-group: free
        float2 qb = q[j+1][fl];
        a0 = fmaf(__builtin_amdgcn_rcpf(1.0f + p0.x*qa.x),
                  __builtin_amdgcn_logf(1.0f + p0.y*qa.y), a0);
        b0 = fmaf(__builtin_amdgcn_rcpf(1.0f + p1.x*qa.x),
                  __builtin_amdgcn_logf(1.0f + p1.y*qa.y), b0);
        a1 = fmaf(__builtin_amdgcn_rcpf(1.0f + p0.x*qb.x),
                  __builtin_amdgcn_logf(1.0f + p0.y*qb.y), a1);
        b1 = fmaf(__builtin_amdgcn_rcpf(1.0f + p1.x*qb.x),
                  __builtin_amdgcn_logf(1.0f + p1.y*qb.y), b1);
    }
    float aA = a0 + a1, aB = b0 + b1;
    {   // remove self-loop terms (j == i)
        float2 qv0 = q[ig][fl];
        aA -= __builtin_amdgcn_rcpf(1.0f + p0.x*qv0.x) *
              __builtin_amdgcn_logf(1.0f + p0.y*qv0.y);
        float2 qv1 = q[ig+32][fl];
        aB -= __builtin_amdgcn_rcpf(1.0f + p1.x*qv1.x) *
              __builtin_amdgcn_logf(1.0f + p1.y*qv1.y);
    }
    aA *= LN2; aB *= LN2;               // log2 -> ln once, outside the sum
    if (agg) {
        agg[(base + ig) * FD + f]      = aA;
        agg[(base + ig + 32) * FD + f] = aB;
    }

    // ---- BN partial stats: reduce 64 i per f in-block, plain stores ----
    __syncthreads();                    // all q reads done; alias as scratch
    float* sm = (float*)q;              // 2048 floats available, need 1024
    sm[tid]      = aA + aB;
    sm[NT + tid] = aA*aA + aB*aB;
    __syncthreads();
    if (tid < FS) {
        float sv = 0.f, qv = 0.f;
        #pragma unroll
        for (int r = 0; r < 32; ++r) {
            sv += sm[r * FS + tid];
            qv += sm[NT + r * FS + tid];
        }
        pS [s * FD + fq * FS + tid] = sv;   // distinct slot per block: no atomics
        pSS[s * FD + fq * FS + tid] = qv;
    }
    aOut0 = aA; aOut1 = aB;
}

// ONE persistent kernel: L1(gemm+edge) -> grid barrier -> x1-in-LDS +
// L2(gemm+edge, output stays in VGPRs) -> grid barrier -> epilogue.
// P/Q, x1, agg2 never touch HBM; 1 launch instead of 3.
__global__ __launch_bounds__(NT, 4) void fused_kernel(
    const float* __restrict__ X0, const float* __restrict__ C,
    const float* __restrict__ Wf1, const float* __restrict__ bf1,
    const float* __restrict__ Ws1, const float* __restrict__ bs1,
    const float* __restrict__ g1, const float* __restrict__ be1,
    const float* __restrict__ Wf2, const float* __restrict__ bf2,
    const float* __restrict__ Ws2, const float* __restrict__ bs2,
    const float* __restrict__ g2, const float* __restrict__ be2,
    float* __restrict__ agg1,
    float* __restrict__ pS1, float* __restrict__ pSS1,
    float* __restrict__ pS2, float* __restrict__ pSS2,
    unsigned* __restrict__ bar1, unsigned* __restrict__ bar2,
    float* __restrict__ out)
{
    __shared__ __align__(16) float xs[NA][XPAD];  // 33 KB: x0, then x1 in place
    __shared__ float4 wlds[FD][FS];               // 32 KB: W1, then W2 slice
    __shared__ float2 q[NA][FS];                  //  8 KB (aliased as scratch)
    __shared__ float2 cs[NA];                     // 0.5 KB
    __shared__ float bnsc[FD], bnsh[FD];          //  1 KB   (total 74.5 KB -> 2/CU)

    const int tid = threadIdx.x, bid = blockIdx.x;
    const int s = bid & (NS - 1), fq = bid >> 6;  // sample f-slices -> same XCD
    const int fl = tid & (FS - 1), ig = tid >> 4;
    const int f  = fq * FS + fl;
    const int base = s * NA;

    // ---- phase 1: stage + layer 1 ----
    stage_w(wlds, Wf1, Ws1, fq, tid);
    const float4* Xv = (const float4*)(X0 + base * FD);
    for (int idx = tid; idx < NA * FD / 4; idx += NT) {
        int n = idx >> 5, k4 = idx & 31;
        *(float4*)&xs[n][k4 * 4] = Xv[idx];
    }
    if (tid < NA) cs[tid] = ((const float2*)C)[base + tid];
    __syncthreads();
    float d0, d1;
    layer_body(xs, cs, q, wlds, Wf1, Ws1, bf1, bs1, tid, s, fq,
               agg1, pS1, pSS1, d0, d1);

    grid_barrier(bar1, MAGIC1, tid, bid);   // agg1 + stats1 partials visible

    // ---- phase 2: W2 restage + stats1 reduce + x1 in place + layer 2 ----
    stage_w(wlds, Wf2, Ws2, fq, tid);
    {   // stats1 partial reduce, all 512 threads (4 sample-groups x 128 f)
        int fr = tid & (FD - 1), sq = tid >> 7;
        float sv = 0.f, qv = 0.f;
        #pragma unroll
        for (int s2 = 0; s2 < NS / 4; ++s2) {
            int si = sq * (NS / 4) + s2;
            sv += pS1[si * FD + fr];
            qv += pSS1[si * FD + fr];
        }
        float* sm = (float*)q;
        sm[tid] = sv;
        sm[NT + tid] = qv;
    }
    __syncthreads();
    if (tid < FD) {
        const float* sm = (const float*)q;
        float sv = sm[tid] + sm[FD + tid] + sm[2*FD + tid] + sm[3*FD + tid];
        float qv = sm[NT + tid] + sm[NT + FD + tid] + sm[NT + 2*FD + tid] + sm[NT + 3*FD + tid];
        float m  = sv * (1.0f / NN);
        float v  = qv * (1.0f / NN) - m * m;
        float sc = g1[tid] * rsqrtf(v + BN_EPS);
        bnsc[tid] = sc;
        bnsh[tid] = be1[tid] - m * sc;
    }
    __syncthreads();
    const float4* Av = (const float4*)(agg1 + base * FD);
    for (int idx = tid; idx < NA * FD / 4; idx += NT) {
        int n = idx >> 5, k4 = (idx & 31) * 4;
        float4 x = *(const float4*)&xs[n][k4];    // x0 still in LDS
        float4 a = Av[idx];
        float4 r;
        r.x = fmaxf(fmaf(a.x, bnsc[k4 + 0], bnsh[k4 + 0]) + x.x, 0.0f);
        r.y = fmaxf(fmaf(a.y, bnsc[k4 + 1], bnsh[k4 + 1]) + x.y, 0.0f);
        r.z = fmaxf(fmaf(a.z, bnsc[k4 + 2], bnsh[k4 + 2]) + x.z, 0.0f);
        r.w = fmaxf(fmaf(a.w, bnsc[k4 + 3], bnsh[k4 + 3]) + x.w, 0.0f);
        *(float4*)&xs[n][k4] = r;                 // xs := x1 (never hits HBM)
    }
    __syncthreads();
    float aA2, aB2;                               // layer-2 output: registers only
    layer_body(xs, cs, q, wlds, Wf2, Ws2, bf2, bs2, tid, s, fq,
               (float*)nullptr, pS2, pSS2, aA2, aB2);

    grid_barrier(bar2, MAGIC2, tid, bid);   // stats2 partials visible

    // ---- epilogue: stats2 reduce (own 16 f's) + out from registers/LDS ----
    {
        int fr = tid & (FS - 1), sq2 = tid >> 4;  // 32 groups x 2 samples
        float sv = 0.f, qv = 0.f;
        #pragma unroll
        for (int t = 0; t < 2; ++t) {
            int si = sq2 * 2 + t;
            sv += pS2[si * FD + fq * FS + fr];
            qv += pSS2[si * FD + fq * FS + fr];
        }
        float* sm = (float*)q;                    // q dead; barrier sync'd
        sm[tid] = sv;
        sm[NT + tid] = qv;
    }
    __syncthreads();
    if (tid < FS) {
        const float* sm = (const float*)q;
        float sv = 0.f, qv = 0.f;
        #pragma unroll
        for (int g = 0; g < 32; ++g) {
            sv += sm[g * FS + tid];
            qv += sm[NT + g * FS + tid];
        }
        float m  = sv * (1.0f / NN);
        float v  = qv * (1.0f / NN) - m * m;
        float sc = g2[fq * FS + tid] * rsqrtf(v + BN_EPS);
        bnsc[tid] = sc;
        bnsh[tid] = be2[fq * FS + tid] - m * sc;
    }
    __syncthreads();
    {
        float sc = bnsc[fl], sh = bnsh[fl];
        out[(base + ig) * FD + f]      = fmaxf(fmaf(aA2, sc, sh) + xs[ig][f], 0.0f);
        out[(base + ig + 32) * FD + f] = fmaxf(fmaf(aB2, sc, sh) + xs[ig + 32][f], 0.0f);
    }
}

extern "C" void kernel_launch(void* const* d_in, const int* in_sizes, int n_in,
                              void* d_out, int out_size, void* d_ws, size_t ws_size,
                              hipStream_t stream) {
    const float* gnn_in  = (const float*)d_in[0];
    const float* centers = (const float*)d_in[1];
    // d_in[2]=src, d_in[3]=dst: structure known (fully connected per sample) — unused
    const float* Wf1 = (const float*)d_in[4];
    const float* bf1 = (const float*)d_in[5];
    const float* Ws1 = (const float*)d_in[6];
    const float* bs1 = (const float*)d_in[7];
    const float* g1  = (const float*)d_in[8];
    const float* be1 = (const float*)d_in[9];
    const float* Wf2 = (const float*)d_in[10];
    const float* bf2 = (const float*)d_in[11];
    const float* Ws2 = (const float*)d_in[12];
    const float* bs2 = (const float*)d_in[13];
    const float* g2  = (const float*)d_in[14];
    const float* be2 = (const float*)d_in[15];

    char* ws = (char*)d_ws;
    float*    agg1 = (float*)(ws);                              // 2 MB
    float*    pS1  = (float*)(ws + (2 << 20));                  // 32 KB
    float*    pSS1 = (float*)(ws + (2 << 20) + (32 << 10));     // 32 KB
    float*    pS2  = (float*)(ws + (2 << 20) + (64 << 10));     // 32 KB
    float*    pSS2 = (float*)(ws + (2 << 20) + (96 << 10));     // 32 KB
    unsigned* bar1 = (unsigned*)(ws + (2 << 20) + (128 << 10)); // 2 KB
    unsigned* bar2 = (unsigned*)(ws + (2 << 20) + (132 << 10)); // 2 KB

    fused_kernel<<<NB, NT, 0, stream>>>(
        gnn_in, centers,
        Wf1, bf1, Ws1, bs1, g1, be1,
        Wf2, bf2, Ws2, bs2, g2, be2,
        agg1, pS1, pSS1, pS2, pSS2, bar1, bar2, (float*)d_out);
}

// Round 7
// 134.484 us; speedup vs baseline: 2.7965x; 2.7965x over previous
//
#include <hip/hip_runtime.h>

constexpr int NS = 64;          // samples
constexpr int NA = 64;          // agents per sample
constexpr int NN = NS * NA;     // 4096 nodes
constexpr int FD = 128;         // feature dim
constexpr int ZD = 2 * FD + 2;  // 258
constexpr int FS = 16;          // feature-slice width per block
constexpr int NB = NS * (FD / FS); // 512 blocks = (sample, f-slice)
constexpr int NT = 256;         // threads per block: 16 fl x 16 ig, 4 nodes/thread
constexpr int XPAD = 132;       // xs row stride: 528B = 33*16 (float4-aligned), +4 bank skew
constexpr float BN_EPS = 1e-5f;
constexpr float L2E = 1.44269504088896f;
constexpr float LN2 = 0.69314718055995f;

// Stage this block's 16-feature weight slice into LDS (R3/R6-proven path):
// wlds[k][fr] = {Wf[f][k], Wf[f][k+128], Ws[f][k], Ws[f][k+128]}, f = fq*16+fr.
// Reads: 16-row gather, L1/L2-hot (132KB slab shared by 64 blocks).
// Writes: contiguous ds_write_b128, 2-way bank alias (free).
__device__ __forceinline__ void stage_w(
    float4 (*wlds)[FS], const float* __restrict__ Wf, const float* __restrict__ Ws,
    int fq, int tid)
{
    for (int i = tid; i < FD * FS; i += NT) {
        int k = i >> 4, fr = i & (FS - 1);
        int row = (fq * FS + fr) * ZD;
        wlds[k][fr] = make_float4(Wf[row + k], Wf[row + FD + k],
                                  Ws[row + k], Ws[row + FD + k]);
    }
}

// Fused CGConv layer for block (s, fq). 4 nodes/thread: thread (fl, ig) owns
// nodes {ig, ig+16, ig+32, ig+48} at feature f = fq*16+fl. GEMM is LDS-issue-
// bound: 8 ds_read_b128 per 4k-chunk now serve 4 nodes (2/node, was 3/node).
// Edge phase amortizes each q[j] LDS read across 4 targets. P stays in VGPRs,
// Q in the 8KB LDS tile; per-block BN partial stores (no atomics, no zeroing).
__device__ __forceinline__ void layer_body(
    const float (*xs)[XPAD], const float2* cs, float2 (*q)[FS],
    const float4 (*wlds)[FS],
    const float* __restrict__ Wf, const float* __restrict__ Ws,
    const float* __restrict__ bf, const float* __restrict__ bs,
    int tid, int s, int fq,
    float* __restrict__ agg, float* __restrict__ pS, float* __restrict__ pSS)
{
    const int fl = tid & (FS - 1);
    const int ig = tid >> 4;            // 0..15 -> nodes ig + 16*t
    const int f  = fq * FS + fl;
    const int base = s * NA;

    float aPf[4] = {0,0,0,0}, aQf[4] = {0,0,0,0};
    float aPs[4] = {0,0,0,0}, aQs[4] = {0,0,0,0};
    #pragma unroll 2
    for (int k = 0; k < FD; k += 4) {
        float4 w0 = wlds[k + 0][fl];    // 256B/wave, 2-way bank alias: free
        float4 w1 = wlds[k + 1][fl];
        float4 w2 = wlds[k + 2][fl];
        float4 w3 = wlds[k + 3][fl];
        #pragma unroll
        for (int t = 0; t < 4; ++t) {
            float4 x = *(const float4*)&xs[ig + 16 * t][k];  // 4 rows/wave, skewed
            aPf[t] = fmaf(x.x, w0.x, aPf[t]); aQf[t] = fmaf(x.x, w0.y, aQf[t]);
            aPs[t] = fmaf(x.x, w0.z, aPs[t]); aQs[t] = fmaf(x.x, w0.w, aQs[t]);
            aPf[t] = fmaf(x.y, w1.x, aPf[t]); aQf[t] = fmaf(x.y, w1.y, aQf[t]);
            aPs[t] = fmaf(x.y, w1.z, aPs[t]); aQs[t] = fmaf(x.y, w1.w, aQs[t]);
            aPf[t] = fmaf(x.z, w2.x, aPf[t]); aQf[t] = fmaf(x.z, w2.y, aQf[t]);
            aPs[t] = fmaf(x.z, w2.z, aPs[t]); aQs[t] = fmaf(x.z, w2.w, aQs[t]);
            aPf[t] = fmaf(x.w, w3.x, aPf[t]); aQf[t] = fmaf(x.w, w3.y, aQf[t]);
            aPs[t] = fmaf(x.w, w3.z, aPs[t]); aQs[t] = fmaf(x.w, w3.w, aQs[t]);
        }
    }
    float we0 = Wf[f*ZD + 2*FD], we1 = Wf[f*ZD + 2*FD + 1];
    float ws0 = Ws[f*ZD + 2*FD], ws1 = Ws[f*ZD + 2*FD + 1];
    float bfv = bf[f], bsv = bs[f];
    float2 p[4];
    #pragma unroll
    for (int t = 0; t < 4; ++t) {
        int n = ig + 16 * t;
        float2 c = cs[n];
        float cf = c.x * we0 + c.y * we1;
        float cg = c.x * ws0 + c.y * ws1;
        float Pf = aPf[t] + cf + bfv, Ps = aPs[t] + cg + bsv;
        float Qf = aQf[t] - cf,       Qs = aQs[t] - cg;
        // exp-domain: sigma = rcp(1+e^{-P}e^{-Q}), softplus*log2e = log2(1+e^{Ps}e^{Qs})
        p[t] = make_float2(__builtin_amdgcn_exp2f(-Pf * L2E),
                           __builtin_amdgcn_exp2f( Ps * L2E));
        q[n][fl] = make_float2(__builtin_amdgcn_exp2f(-Qf * L2E),
                               __builtin_amdgcn_exp2f( Qs * L2E));
    }
    __syncthreads();

    // ---- edge aggregation: 4 i's, all 64 j; dual chains per node (order as R6) ----
    float e0[4] = {0,0,0,0}, e1[4] = {0,0,0,0};
    #pragma unroll 2
    for (int j = 0; j < NA; j += 2) {
        float2 qa = q[j][fl];            // one LDS read serves 4 targets
        float2 qb = q[j + 1][fl];
        #pragma unroll
        for (int t = 0; t < 4; ++t) {
            e0[t] = fmaf(__builtin_amdgcn_rcpf(1.0f + p[t].x * qa.x),
                         __builtin_amdgcn_logf(1.0f + p[t].y * qa.y), e0[t]);
            e1[t] = fmaf(__builtin_amdgcn_rcpf(1.0f + p[t].x * qb.x),
                         __builtin_amdgcn_logf(1.0f + p[t].y * qb.y), e1[t]);
        }
    }
    float av[4];
    float ssum = 0.f, qsum = 0.f;
    #pragma unroll
    for (int t = 0; t < 4; ++t) {
        int n = ig + 16 * t;
        float a = e0[t] + e1[t];
        float2 qv = q[n][fl];            // remove self-loop term (j == i)
        a -= __builtin_amdgcn_rcpf(1.0f + p[t].x * qv.x) *
             __builtin_amdgcn_logf(1.0f + p[t].y * qv.y);
        a *= LN2;                        // log2 -> ln once, outside the sum
        agg[(base + n) * FD + f] = a;
        av[t] = a;
        ssum += a; qsum += a * a;
    }

    // ---- BN partial stats: reduce 64 i per f in-block, plain stores ----
    __syncthreads();                     // all q reads done; alias as scratch
    float* sm = (float*)q;               // 2048 floats available, need 512
    sm[tid]      = ssum;
    sm[NT + tid] = qsum;
    __syncthreads();
    if (tid < FS) {
        float sv = 0.f, qv = 0.f;
        #pragma unroll
        for (int r = 0; r < 16; ++r) {
            sv += sm[r * FS + tid];
            qv += sm[NT + r * FS + tid];
        }
        pS [s * FD + fq * FS + tid] = sv;   // distinct slot per block: no atomics
        pSS[s * FD + fq * FS + tid] = qv;
    }
    (void)av;
}

// Layer 1: stage x0 tile + W1 slice, fused GEMM+edge -> agg1 + partial stats1.
__global__ __launch_bounds__(NT) void layer1_kernel(
    const float* __restrict__ X0, const float* __restrict__ C,
    const float* __restrict__ Wf, const float* __restrict__ Ws,
    const float* __restrict__ bf, const float* __restrict__ bs,
    float* __restrict__ agg, float* __restrict__ pS, float* __restrict__ pSS)
{
    __shared__ __align__(16) float xs[NA][XPAD];  // 33 KB
    __shared__ float4 wlds[FD][FS];               // 32 KB
    __shared__ float2 q[NA][FS];                  //  8 KB
    __shared__ float2 cs[NA];                     // 0.5 KB  (~74 KB -> 2 blocks/CU)
    int tid = threadIdx.x, bid = blockIdx.x;
    int s = bid & (NS - 1), fq = bid >> 6;  // 8 f-slices of a sample -> same XCD
    int base = s * NA;
    stage_w(wlds, Wf, Ws, fq, tid);
    const float4* Xv = (const float4*)(X0 + base * FD);
    for (int idx = tid; idx < NA * FD / 4; idx += NT) {
        int n = idx >> 5, k4 = idx & 31;
        *(float4*)&xs[n][k4 * 4] = Xv[idx];
    }
    if (tid < NA) cs[tid] = ((const float2*)C)[base + tid];
    __syncthreads();
    layer_body(xs, cs, q, wlds, Wf, Ws, bf, bs, tid, s, fq, agg, pS, pSS);
}

// Layer 2: stage W2 slice + parallel stats1 reduce, x1 = relu(BN1(agg1)+x0)
// into LDS + global, then fused layer -> agg2 + partial stats2.
__global__ __launch_bounds__(NT) void layer2_kernel(
    const float* __restrict__ X0, const float* __restrict__ agg1,
    const float* __restrict__ C,
    const float* __restrict__ pS1, const float* __restrict__ pSS1,
    const float* __restrict__ g1, const float* __restrict__ be1,
    const float* __restrict__ Wf, const float* __restrict__ Ws,
    const float* __restrict__ bf, const float* __restrict__ bs,
    float* __restrict__ x1, float* __restrict__ agg2,
    float* __restrict__ pS2, float* __restrict__ pSS2)
{
    __shared__ __align__(16) float xs[NA][XPAD];
    __shared__ float4 wlds[FD][FS];
    __shared__ float2 q[NA][FS];
    __shared__ float2 cs[NA];
    __shared__ float bnsc[FD], bnsh[FD];
    int tid = threadIdx.x, bid = blockIdx.x;
    int s = bid & (NS - 1), fq = bid >> 6;
    int base = s * NA;
    stage_w(wlds, Wf, Ws, fq, tid);
    {   // stats1 partial reduce: 256 threads = 128 f x 2 sample-halves
        int fr = tid & (FD - 1), sq = tid >> 7;
        float sv = 0.f, qv = 0.f;
        #pragma unroll
        for (int s2 = 0; s2 < NS / 2; ++s2) {
            int si = sq * (NS / 2) + s2;
            sv += pS1[si * FD + fr];
            qv += pSS1[si * FD + fr];
        }
        float* sm = (float*)q;           // scratch (q dead until layer_body)
        sm[tid] = sv;
        sm[2 * NT + tid] = qv;
    }
    if (tid < NA) cs[tid] = ((const float2*)C)[base + tid];
    __syncthreads();
    if (tid < FD) {
        const float* sm = (const float*)q;
        float sv = sm[tid] + sm[FD + tid];
        float qv = sm[2 * NT + tid] + sm[2 * NT + FD + tid];
        float m  = sv * (1.0f / NN);
        float v  = qv * (1.0f / NN) - m * m;
        float sc = g1[tid] * rsqrtf(v + BN_EPS);
        bnsc[tid] = sc;
        bnsh[tid] = be1[tid] - m * sc;
    }
    __syncthreads();
    const float4* Xv  = (const float4*)(X0 + base * FD);
    const float4* Av  = (const float4*)(agg1 + base * FD);
    float4*       X1v = (float4*)(x1 + base * FD);
    for (int idx = tid; idx < NA * FD / 4; idx += NT) {
        int n = idx >> 5, k4 = (idx & 31) * 4;
        float4 x = Xv[idx], a = Av[idx];
        float4 r;
        r.x = fmaxf(fmaf(a.x, bnsc[k4 + 0], bnsh[k4 + 0]) + x.x, 0.0f);
        r.y = fmaxf(fmaf(a.y, bnsc[k4 + 1], bnsh[k4 + 1]) + x.y, 0.0f);
        r.z = fmaxf(fmaf(a.z, bnsc[k4 + 2], bnsh[k4 + 2]) + x.z, 0.0f);
        r.w = fmaxf(fmaf(a.w, bnsc[k4 + 3], bnsh[k4 + 3]) + x.w, 0.0f);
        *(float4*)&xs[n][k4] = r;
        X1v[idx] = r;                   // x1 for the epilogue kernel
    }
    __syncthreads();
    layer_body(xs, cs, q, wlds, Wf, Ws, bf, bs, tid, s, fq, agg2, pS2, pSS2);
}

// Epilogue: parallel stats2 reduce per block, out = relu(BN2(agg2) + x1).
__global__ __launch_bounds__(NT) void out_kernel(
    const float4* __restrict__ x1, const float4* __restrict__ agg2,
    const float* __restrict__ pS2, const float* __restrict__ pSS2,
    const float* __restrict__ g2, const float* __restrict__ be2,
    float4* __restrict__ out)
{
    __shared__ float sm[4 * NT];
    __shared__ float sc[FD], sh[FD];
    int tid = threadIdx.x;
    {   // 256 threads = 128 f x 2 sample-halves
        int fr = tid & (FD - 1), sq = tid >> 7;
        float sv = 0.f, qv = 0.f;
        #pragma unroll
        for (int s2 = 0; s2 < NS / 2; ++s2) {
            int si = sq * (NS / 2) + s2;
            sv += pS2[si * FD + fr];
            qv += pSS2[si * FD + fr];
        }
        sm[tid] = sv;
        sm[2 * NT + tid] = qv;
    }
    __syncthreads();
    if (tid < FD) {
        float sv = sm[tid] + sm[FD + tid];
        float qv = sm[2 * NT + tid] + sm[2 * NT + FD + tid];
        float m  = sv * (1.0f / NN);
        float v  = qv * (1.0f / NN) - m * m;
        float scl = g2[tid] * rsqrtf(v + BN_EPS);
        sc[tid] = scl;
        sh[tid] = be2[tid] - m * scl;
    }
    __syncthreads();
    int idx = blockIdx.x * NT + tid;    // < NN*FD/4
    int f0 = (idx & 31) * 4;
    float4 xv = x1[idx], av = agg2[idx];
    float4 r;
    r.x = fmaxf(fmaf(av.x, sc[f0 + 0], sh[f0 + 0]) + xv.x, 0.0f);
    r.y = fmaxf(fmaf(av.y, sc[f0 + 1], sh[f0 + 1]) + xv.y, 0.0f);
    r.z = fmaxf(fmaf(av.z, sc[f0 + 2], sh[f0 + 2]) + xv.z, 0.0f);
    r.w = fmaxf(fmaf(av.w, sc[f0 + 3], sh[f0 + 3]) + xv.w, 0.0f);
    out[idx] = r;
}

extern "C" void kernel_launch(void* const* d_in, const int* in_sizes, int n_in,
                              void* d_out, int out_size, void* d_ws, size_t ws_size,
                              hipStream_t stream) {
    const float* gnn_in  = (const float*)d_in[0];
    const float* centers = (const float*)d_in[1];
    // d_in[2]=src, d_in[3]=dst: structure known (fully connected per sample) — unused
    const float* Wf1 = (const float*)d_in[4];
    const float* bf1 = (const float*)d_in[5];
    const float* Ws1 = (const float*)d_in[6];
    const float* bs1 = (const float*)d_in[7];
    const float* g1  = (const float*)d_in[8];
    const float* be1 = (const float*)d_in[9];
    const float* Wf2 = (const float*)d_in[10];
    const float* bf2 = (const float*)d_in[11];
    const float* Ws2 = (const float*)d_in[12];
    const float* bs2 = (const float*)d_in[13];
    const float* g2  = (const float*)d_in[14];
    const float* be2 = (const float*)d_in[15];

    char* ws = (char*)d_ws;
    float* agg1  = (float*)(ws);                             // 2 MB
    float* agg2  = (float*)(ws + (2 << 20));                 // 2 MB
    float* x1    = (float*)(ws + (4 << 20));                 // 2 MB
    float* p1S   = (float*)(ws + (6 << 20));                 // 32 KB
    float* p1SS  = (float*)(ws + (6 << 20) + (32 << 10));    // 32 KB
    float* p2S   = (float*)(ws + (6 << 20) + (64 << 10));    // 32 KB
    float* p2SS  = (float*)(ws + (6 << 20) + (96 << 10));    // 32 KB

    layer1_kernel<<<NB, NT, 0, stream>>>(gnn_in, centers, Wf1, Ws1, bf1, bs1,
                                         agg1, p1S, p1SS);
    layer2_kernel<<<NB, NT, 0, stream>>>(gnn_in, agg1, centers, p1S, p1SS, g1, be1,
                                         Wf2, Ws2, bf2, bs2, x1, agg2, p2S, p2SS);
    out_kernel<<<NN * FD / 4 / NT, NT, 0, stream>>>(
        (const float4*)x1, (const float4*)agg2, p2S, p2SS, g2, be2, (float4*)d_out);
}